// Round 7
// baseline (67.757 us; speedup 1.0000x reference)
//
#include <hip/hip_runtime.h>

#define D256 256
#define KT 8
#define S_SEQ 1024
#define OUTSEQ 512

// ---------------- prep: transpose/pack tables ----------------
// MW[j][o]   = {M[o][j], res_W[o][j]}
// PIt4[j][i] = {P[i][j], 1/p, 2*cos(2pi/p), 0}, p = i*256+j+2
__global__ __launch_bounds__(256) void k_prep(const float* __restrict__ M,
                                              const float* __restrict__ resW,
                                              const float* __restrict__ P,
                                              float2* __restrict__ MW,
                                              float4* __restrict__ PIt4) {
  const int j = blockIdx.x;
  const int t = threadIdx.x;
  MW[j * D256 + t] = make_float2(M[t * D256 + j], resW[t * D256 + j]);
  const float p = (float)(t * D256 + j + 2);
  const float ip = 1.0f / p;                           // precise div
  const float cb2 = 2.0f * __builtin_amdgcn_cosf(ip);  // v_cos takes revolutions
  PIt4[j * D256 + t] = make_float4(P[t * D256 + j], ip, cb2, 0.0f);
}

// ---------------- fused k_AB: GEMM -> LN -> cos-einsum ----------------
// grid 512 = (k-tile kt) x (i-half ih); 1024 threads.
// Phase A redundant per half (LN couples full row); phase B j-split 8 ways,
// each block produces its i-half of T.
__global__ __launch_bounds__(1024, 8) void k_AB(const float* __restrict__ x,
                                                const float2* __restrict__ MW,
                                                const float4* __restrict__ PIt4,
                                                const float* __restrict__ gamma,
                                                const float* __restrict__ beta,
                                                float* __restrict__ T,
                                                float* __restrict__ rfeat) {
  __shared__ float Xs[D256][12];         // [col][row] padded; 12 KB
  __shared__ float2 red2[4][KT][D256];   // 64 KB (phase A); reused as float[8][8][128] in B
  __shared__ float mu_s[KT], rs_s[KT];
  const int tid = threadIdx.x;
  const int kt = blockIdx.x >> 1;
  const int ih = blockIdx.x & 1;
  const int k0 = kt * KT;

  // ---- stage x tile transposed: [col][row] ----
  {
    const int i = tid & 255;
    const int h = tid >> 8;
    Xs[i][h]     = x[(k0 + h) * D256 + i];
    Xs[i][h + 4] = x[(k0 + h + 4) * D256 + i];
  }
  __syncthreads();

  // ---- phase A (full i, redundant across the two i-half blocks) ----
  {
    const int i = tid & 255;
    const int h = tid >> 8;               // j-quarter
    float aM[KT], aR[KT];
    #pragma unroll
    for (int r = 0; r < KT; ++r) { aM[r] = 0.f; aR[r] = 0.f; }
    const float2* mwp = MW + i;
    #pragma unroll 2
    for (int jj = 0; jj < 64; ++jj) {
      const int j = h * 64 + jj;
      const float2 mw = mwp[j * D256];
      const float4 z0 = *(const float4*)&Xs[j][0];   // broadcast b128
      const float4 z1 = *(const float4*)&Xs[j][4];
      aM[0] = fmaf(z0.x, mw.x, aM[0]); aR[0] = fmaf(z0.x, mw.y, aR[0]);
      aM[1] = fmaf(z0.y, mw.x, aM[1]); aR[1] = fmaf(z0.y, mw.y, aR[1]);
      aM[2] = fmaf(z0.z, mw.x, aM[2]); aR[2] = fmaf(z0.z, mw.y, aR[2]);
      aM[3] = fmaf(z0.w, mw.x, aM[3]); aR[3] = fmaf(z0.w, mw.y, aR[3]);
      aM[4] = fmaf(z1.x, mw.x, aM[4]); aR[4] = fmaf(z1.x, mw.y, aR[4]);
      aM[5] = fmaf(z1.y, mw.x, aM[5]); aR[5] = fmaf(z1.y, mw.y, aR[5]);
      aM[6] = fmaf(z1.z, mw.x, aM[6]); aR[6] = fmaf(z1.z, mw.y, aR[6]);
      aM[7] = fmaf(z1.w, mw.x, aM[7]); aR[7] = fmaf(z1.w, mw.y, aR[7]);
    }
    #pragma unroll
    for (int r = 0; r < KT; ++r) red2[h][r][i] = make_float2(aM[r], aR[r]);
    __syncthreads();
    #pragma unroll
    for (int p = 0; p < 2; ++p) {
      const int r = h * 2 + p;
      const float2 a0 = red2[0][r][i], a1 = red2[1][r][i];
      const float2 a2 = red2[2][r][i], a3 = red2[3][r][i];
      if ((i >> 7) == ih)                 // wave-uniform predicate
        rfeat[(k0 + r) * D256 + i] = a0.y + a1.y + a2.y + a3.y;
      Xs[i][r] = a0.x + a1.x + a2.x + a3.x;   // pre-LN Z (full)
    }
  }
  __syncthreads();

  // ---- LN stats: wave w reduces row w ----
  {
    const int w = tid >> 6, lane = tid & 63;
    if (w < KT) {
      float s = 0.f, sq = 0.f;
      #pragma unroll
      for (int l = 0; l < 4; ++l) {
        const float v = Xs[lane + 64 * l][w];
        s += v;
        sq = fmaf(v, v, sq);
      }
      #pragma unroll
      for (int off = 32; off; off >>= 1) {
        s += __shfl_down(s, off);
        sq += __shfl_down(sq, off);
      }
      if (lane == 0) {
        const float m = s * (1.0f / 256.0f);
        const float var = sq * (1.0f / 256.0f) - m * m;
        mu_s[w] = m;
        rs_s[w] = rsqrtf(var + 1e-5f);
      }
    }
  }
  __syncthreads();
  {
    const int i = tid & 255;
    const int h = tid >> 8;
    const float g = gamma[i], be = beta[i];
    #pragma unroll
    for (int p = 0; p < 2; ++p) {
      const int r = h + 4 * p;
      Xs[i][r] = (Xs[i][r] - mu_s[r]) * rs_s[r] * g + be;
    }
  }
  __syncthreads();

  // ---- phase B: own i-half, j split 8 ways, folded-P Chebyshev ----
  {
    const int je = tid >> 7;              // j-eighth (wave-uniform)
    const int il = tid & 127;
    const int ib = ih * 128 + il;         // global i
    float accT[KT] = {};
    const float kf0 = (float)k0;
    const float4* pip = PIt4 + ib;
    #pragma unroll 2
    for (int jj = 0; jj < 32; ++jj) {
      const int j = je * 32 + jj;
      const float4 pi = pip[j * D256];               // {P, 1/p, cb2, 0}
      const float4 z0 = *(const float4*)&Xs[j][0];   // broadcast b128
      const float4 z1 = *(const float4*)&Xs[j][4];
      const float a = kf0 * pi.y;
      float c0 = __builtin_amdgcn_cosf(__builtin_amdgcn_fractf(a)) * pi.x;
      float c1 = __builtin_amdgcn_cosf(__builtin_amdgcn_fractf(a + pi.y)) * pi.x;
      accT[0] = fmaf(z0.x, c0, accT[0]);
      accT[1] = fmaf(z0.y, c1, accT[1]);
      float c2;
      c2 = fmaf(pi.z, c1, -c0); accT[2] = fmaf(z0.z, c2, accT[2]); c0 = c1; c1 = c2;
      c2 = fmaf(pi.z, c1, -c0); accT[3] = fmaf(z0.w, c2, accT[3]); c0 = c1; c1 = c2;
      c2 = fmaf(pi.z, c1, -c0); accT[4] = fmaf(z1.x, c2, accT[4]); c0 = c1; c1 = c2;
      c2 = fmaf(pi.z, c1, -c0); accT[5] = fmaf(z1.y, c2, accT[5]); c0 = c1; c1 = c2;
      c2 = fmaf(pi.z, c1, -c0); accT[6] = fmaf(z1.z, c2, accT[6]); c0 = c1; c1 = c2;
      c2 = fmaf(pi.z, c1, -c0); accT[7] = fmaf(z1.w, c2, accT[7]);
    }
    float* red = (float*)red2;            // [8][8][128]
    #pragma unroll
    for (int r = 0; r < KT; ++r) red[(je * 8 + r) * 128 + il] = accT[r];
    __syncthreads();
    {
      const int r = tid >> 7;
      const int i2 = tid & 127;
      float s = 0.f;
      #pragma unroll
      for (int e = 0; e < 8; ++e) s += red[(e * 8 + r) * 128 + i2];
      T[(k0 + r) * D256 + ih * 128 + i2] = s;
    }
  }
}

// ---------------- stage C1: split-s partial GEMM, t-tile 16, s-chunk 64 ----
// grid = b(2) x tt(32) x sc(16) = 1024 blocks; 256 thr = d
__global__ __launch_bounds__(256) void k_C1(const float* __restrict__ T,
                                            const float* __restrict__ rfeat,
                                            const float* __restrict__ Linker,
                                            const float* __restrict__ rLinker,
                                            float* __restrict__ part) {
  __shared__ float Ls[64][16];
  __shared__ float rLs[64][16];
  const int bid = blockIdx.x;
  const int sc = bid & 15;
  const int tt = (bid >> 4) & 31;
  const int b  = bid >> 9;
  const int t0 = tt * 16;
  const int s0 = sc * 64;
  const int d  = threadIdx.x;

  // stage Linker chunks: 64 rows x 16 cols each, one float4/thread/table
  {
    const int row = threadIdx.x >> 2;
    const int c4  = (threadIdx.x & 3) * 4;
    *(float4*)&Ls[row][c4]  = *(const float4*)&Linker[(s0 + row) * OUTSEQ + t0 + c4];
    *(float4*)&rLs[row][c4] = *(const float4*)&rLinker[(s0 + row) * OUTSEQ + t0 + c4];
  }
  __syncthreads();

  float acc[16] = {};
  const float* Tp = &T[(b * S_SEQ + s0) * D256 + d];
  const float* Rp = &rfeat[(b * S_SEQ + s0) * D256 + d];
  #pragma unroll 4
  for (int s = 0; s < 64; ++s) {
    const float tv = Tp[s * D256];
    const float rv = Rp[s * D256];
    #pragma unroll
    for (int q = 0; q < 4; ++q) {
      const float4 l = *(const float4*)&Ls[s][q * 4];    // broadcast
      const float4 r = *(const float4*)&rLs[s][q * 4];
      acc[q * 4 + 0] = fmaf(tv, l.x, acc[q * 4 + 0]);
      acc[q * 4 + 0] = fmaf(rv, r.x, acc[q * 4 + 0]);
      acc[q * 4 + 1] = fmaf(tv, l.y, acc[q * 4 + 1]);
      acc[q * 4 + 1] = fmaf(rv, r.y, acc[q * 4 + 1]);
      acc[q * 4 + 2] = fmaf(tv, l.z, acc[q * 4 + 2]);
      acc[q * 4 + 2] = fmaf(rv, r.z, acc[q * 4 + 2]);
      acc[q * 4 + 3] = fmaf(tv, l.w, acc[q * 4 + 3]);
      acc[q * 4 + 3] = fmaf(rv, r.w, acc[q * 4 + 3]);
    }
  }

  const int rowbase = b * 512 + t0;
  #pragma unroll
  for (int u = 0; u < 16; ++u)
    part[(((sc << 10) + rowbase + u) << 8) + d] = acc[u];
}

// ---------------- stage C2: reduce the 16 s-chunk partials ----------------
__global__ __launch_bounds__(256) void k_C2(const float* __restrict__ part,
                                            float* __restrict__ out) {
  const int row = blockIdx.x;   // 0..1023
  const int d   = threadIdx.x;
  float s = 0.f;
  #pragma unroll
  for (int sc = 0; sc < 16; ++sc)
    s += part[(((sc << 10) + row) << 8) + d];
  out[(row << 8) + d] = s;
}

extern "C" void kernel_launch(void* const* d_in, const int* in_sizes, int n_in,
                              void* d_out, int out_size, void* d_ws, size_t ws_size,
                              hipStream_t stream) {
  const float* x       = (const float*)d_in[0];
  const float* M       = (const float*)d_in[1];
  const float* P       = (const float*)d_in[2];
  const float* Linker  = (const float*)d_in[3];
  const float* gamma   = (const float*)d_in[4];
  const float* beta    = (const float*)d_in[5];
  const float* resW    = (const float*)d_in[6];
  const float* rLinker = (const float*)d_in[7];
  float* out = (float*)d_out;

  char* ws = (char*)d_ws;
  float2* MW    = (float2*)(ws);                        // 0.5 MB
  float4* PIt4  = (float4*)(ws + 512 * 1024);           // 1 MB
  float*  T     = (float*)(ws + 1536 * 1024);           // 2 MB
  float*  rfeat = (float*)(ws + 3584 * 1024);           // 2 MB
  float*  part  = (float*)(ws + 5632 * 1024);           // 16 MB

  hipLaunchKernelGGL(k_prep, dim3(256),  dim3(256),  0, stream, M, resW, P, MW, PIt4);
  hipLaunchKernelGGL(k_AB,   dim3(512),  dim3(1024), 0, stream, x, MW, PIt4, gamma, beta, T, rfeat);
  hipLaunchKernelGGL(k_C1,   dim3(1024), dim3(256),  0, stream, T, rfeat, Linker, rLinker, part);
  hipLaunchKernelGGL(k_C2,   dim3(1024), dim3(256),  0, stream, part, out);
}

// Round 8
// 49.785 us; speedup vs baseline: 1.3610x; 1.3610x over previous
//
#include <hip/hip_runtime.h>

#define D256 256
#define KT 8
#define S_SEQ 1024
#define OUTSEQ 512

typedef __attribute__((ext_vector_type(8))) short bf16x8;
typedef __attribute__((ext_vector_type(8))) unsigned short u16x8;
typedef __attribute__((ext_vector_type(4))) float f32x4;

__device__ inline unsigned short f2bf(float f) {          // RNE fp32->bf16
  unsigned u = __float_as_uint(f);
  return (unsigned short)((u + 0x7fffu + ((u >> 16) & 1u)) >> 16);
}

// ---------------- prep ----------------
// blocks 0..255:   MW[j][o] = {M[o][j], res_W[o][j]};  PIt4[j][i] = {P[i][j], 1/p, cb2, 0}
// blocks 256..511: LinkTb[t][s] = bf16( s<1024 ? Linker[s][t] : rLinker[s-1024][t] )
__global__ __launch_bounds__(256) void k_prep(const float* __restrict__ M,
                                              const float* __restrict__ resW,
                                              const float* __restrict__ P,
                                              const float* __restrict__ Linker,
                                              const float* __restrict__ rLinker,
                                              float2* __restrict__ MW,
                                              float4* __restrict__ PIt4,
                                              unsigned short* __restrict__ LinkTb) {
  __shared__ float tl[64][65];
  const int tid = threadIdx.x;
  if (blockIdx.x < 256) {
    const int j = blockIdx.x;
    const int t = tid;
    MW[j * D256 + t] = make_float2(M[t * D256 + j], resW[t * D256 + j]);
    const float p = (float)(t * D256 + j + 2);
    const float ip = 1.0f / p;
    const float cb2 = 2.0f * __builtin_amdgcn_cosf(ip);   // v_cos takes revolutions
    PIt4[j * D256 + t] = make_float4(P[t * D256 + j], ip, cb2, 0.0f);
    return;
  }
  const int tb = blockIdx.x - 256;      // 0..255
  const int st = tb & 31;               // s-tile (64 rows)
  const int tt = tb >> 5;               // t-tile (64 cols)
  const int s0 = st * 64, t0 = tt * 64;
  const float* src = (s0 < 1024) ? (Linker + (size_t)s0 * OUTSEQ)
                                 : (rLinker + (size_t)(s0 - 1024) * OUTSEQ);
  {
    const int sy = tid >> 2, sx = tid & 3;
    #pragma unroll
    for (int c = 0; c < 4; ++c) {
      const int ci = sx + c * 4;        // 0..15 float4s across 64 cols
      const float4 v = *(const float4*)&src[sy * OUTSEQ + t0 + ci * 4];
      tl[ci * 4 + 0][sy] = v.x;
      tl[ci * 4 + 1][sy] = v.y;
      tl[ci * 4 + 2][sy] = v.z;
      tl[ci * 4 + 3][sy] = v.w;
    }
  }
  __syncthreads();
  {
    const int ty = tid >> 2, tx = tid & 3;
    u16x8 o0, o1;
    #pragma unroll
    for (int e = 0; e < 8; ++e) o0[e] = f2bf(tl[ty][tx * 16 + e]);
    #pragma unroll
    for (int e = 0; e < 8; ++e) o1[e] = f2bf(tl[ty][tx * 16 + 8 + e]);
    unsigned short* dst = LinkTb + (size_t)(t0 + ty) * 2048 + s0 + tx * 16;
    *(u16x8*)dst = o0;
    *(u16x8*)(dst + 8) = o1;
  }
}

// ---------------- fused k_AB: GEMM -> LN -> cos-einsum (round-4 structure) --
// grid 256 (k-tiles of 8), 1024 threads = (j-quarter h) x (col i)
// Outputs packed bf16 transposed: Bt[d][4096], cols [T(2048) | rfeat(2048)]
__global__ __launch_bounds__(1024, 4) void k_AB(const float* __restrict__ x,
                                                const float2* __restrict__ MW,
                                                const float4* __restrict__ PIt4,
                                                const float* __restrict__ gamma,
                                                const float* __restrict__ beta,
                                                unsigned short* __restrict__ Bt) {
  __shared__ float Xs[D256][12];        // [col][row] padded: b128 rows, 12 KB
  __shared__ float red[4][KT][D256];    // 32 KB reduce buffer (reused 3x)
  __shared__ float mu_s[KT], rs_s[KT];
  const int tid = threadIdx.x;
  const int i = tid & 255;
  const int h = tid >> 8;               // j-quarter, wave-uniform
  const int j0 = h * 64;
  const int k0 = blockIdx.x * KT;

  // stage x tile transposed: [col][row]
  Xs[i][h]     = x[(k0 + h) * D256 + i];
  Xs[i][h + 4] = x[(k0 + h + 4) * D256 + i];
  __syncthreads();

  // ---- phase A: partial x@M^T and x@resW^T over j-quarter ----
  float aM[KT], aR[KT];
  #pragma unroll
  for (int r = 0; r < KT; ++r) { aM[r] = 0.f; aR[r] = 0.f; }
  {
    const float2* mwp = MW + i;
    #pragma unroll 8
    for (int jj = 0; jj < 64; ++jj) {
      const int j = j0 + jj;
      const float2 mw = mwp[j * D256];
      const float4 z0 = *(const float4*)&Xs[j][0];   // broadcast b128
      const float4 z1 = *(const float4*)&Xs[j][4];
      aM[0] = fmaf(z0.x, mw.x, aM[0]); aR[0] = fmaf(z0.x, mw.y, aR[0]);
      aM[1] = fmaf(z0.y, mw.x, aM[1]); aR[1] = fmaf(z0.y, mw.y, aR[1]);
      aM[2] = fmaf(z0.z, mw.x, aM[2]); aR[2] = fmaf(z0.z, mw.y, aR[2]);
      aM[3] = fmaf(z0.w, mw.x, aM[3]); aR[3] = fmaf(z0.w, mw.y, aR[3]);
      aM[4] = fmaf(z1.x, mw.x, aM[4]); aR[4] = fmaf(z1.x, mw.y, aR[4]);
      aM[5] = fmaf(z1.y, mw.x, aM[5]); aR[5] = fmaf(z1.y, mw.y, aR[5]);
      aM[6] = fmaf(z1.z, mw.x, aM[6]); aR[6] = fmaf(z1.z, mw.y, aR[6]);
      aM[7] = fmaf(z1.w, mw.x, aM[7]); aR[7] = fmaf(z1.w, mw.y, aR[7]);
    }
  }

  // rfeat partials -> bf16 transposed pack
  #pragma unroll
  for (int r = 0; r < KT; ++r) red[h][r][i] = aR[r];
  __syncthreads();
  if (tid < 256) {
    u16x8 o;
    #pragma unroll
    for (int r = 0; r < KT; ++r)
      o[r] = f2bf(red[0][r][tid] + red[1][r][tid] + red[2][r][tid] + red[3][r][tid]);
    *(u16x8*)(Bt + (size_t)tid * 4096 + 2048 + k0) = o;
  }
  __syncthreads();

  // aM partials -> pre-LN Z into Xs
  #pragma unroll
  for (int r = 0; r < KT; ++r) red[h][r][i] = aM[r];
  __syncthreads();
  #pragma unroll
  for (int p = 0; p < 2; ++p) {
    const int r = h * 2 + p;
    Xs[i][r] = red[0][r][i] + red[1][r][i] + red[2][r][i] + red[3][r][i];
  }
  __syncthreads();

  // LN stats: wave w reduces row w
  const int w = tid >> 6, lane = tid & 63;
  if (w < KT) {
    float s = 0.f, sq = 0.f;
    #pragma unroll
    for (int l = 0; l < 4; ++l) {
      const float v = Xs[lane + 64 * l][w];
      s += v;
      sq = fmaf(v, v, sq);
    }
    #pragma unroll
    for (int off = 32; off; off >>= 1) {
      s += __shfl_down(s, off);
      sq += __shfl_down(sq, off);
    }
    if (lane == 0) {
      const float m = s * (1.0f / 256.0f);
      const float var = sq * (1.0f / 256.0f) - m * m;
      mu_s[w] = m;
      rs_s[w] = rsqrtf(var + 1e-5f);
    }
  }
  __syncthreads();
  {
    const float g = gamma[i], be = beta[i];
    #pragma unroll
    for (int p = 0; p < 2; ++p) {
      const int r = h + 4 * p;
      Xs[i][r] = (Xs[i][r] - mu_s[r]) * rs_s[r] * g + be;
    }
  }
  __syncthreads();

  // ---- phase B: T[k,i] = sum_j Z[k,j]*P[i,j]*cos(2pi*k/p_ij), Chebyshev ----
  float accT[KT] = {};
  const float kf0 = (float)k0, kf1 = (float)(k0 + 1);
  {
    const float4* pip = PIt4 + i;
    #pragma unroll 4
    for (int jj = 0; jj < 64; ++jj) {
      const int j = j0 + jj;
      const float4 pi = pip[j * D256];               // {P, 1/p, cb2, 0}
      const float4 z0 = *(const float4*)&Xs[j][0];   // broadcast b128
      const float4 z1 = *(const float4*)&Xs[j][4];
      const float r0 = __builtin_amdgcn_fractf(kf0 * pi.y);
      const float r1 = __builtin_amdgcn_fractf(kf1 * pi.y);
      float c0 = __builtin_amdgcn_cosf(r0);
      float c1 = __builtin_amdgcn_cosf(r1);
      accT[0] = fmaf(z0.x * pi.x, c0, accT[0]);
      accT[1] = fmaf(z0.y * pi.x, c1, accT[1]);
      float c2;
      c2 = fmaf(pi.z, c1, -c0); accT[2] = fmaf(z0.z * pi.x, c2, accT[2]); c0 = c1; c1 = c2;
      c2 = fmaf(pi.z, c1, -c0); accT[3] = fmaf(z0.w * pi.x, c2, accT[3]); c0 = c1; c1 = c2;
      c2 = fmaf(pi.z, c1, -c0); accT[4] = fmaf(z1.x * pi.x, c2, accT[4]); c0 = c1; c1 = c2;
      c2 = fmaf(pi.z, c1, -c0); accT[5] = fmaf(z1.y * pi.x, c2, accT[5]); c0 = c1; c1 = c2;
      c2 = fmaf(pi.z, c1, -c0); accT[6] = fmaf(z1.z * pi.x, c2, accT[6]); c0 = c1; c1 = c2;
      c2 = fmaf(pi.z, c1, -c0); accT[7] = fmaf(z1.w * pi.x, c2, accT[7]);
    }
  }
  #pragma unroll
  for (int r = 0; r < KT; ++r) red[h][r][i] = accT[r];
  __syncthreads();
  if (tid < 256) {
    u16x8 o;
    #pragma unroll
    for (int r = 0; r < KT; ++r)
      o[r] = f2bf(red[0][r][tid] + red[1][r][tid] + red[2][r][tid] + red[3][r][tid]);
    *(u16x8*)(Bt + (size_t)tid * 4096 + k0) = o;
  }
}

// ---------------- k_Cm: bf16 MFMA GEMM, K split 8 ways ----------------
// out[b*512+t][d] = sum_s LinkTb[t][s]*T/rfeat ; grid 512 = kc8 x dt4 x tt8 x b2
// A frag: lane(m=l&15,q=l>>4) holds A[t0+m][k=q*8+e]; B frag: B[k=q*8+e][d0+n=l&15]
// C/D: col=lane&15, row=(lane>>4)*4+reg  [m89 verified]
__global__ __launch_bounds__(256) void k_Cm(const unsigned short* __restrict__ LinkTb,
                                            const unsigned short* __restrict__ Bt,
                                            float* __restrict__ part) {
  const int bid = blockIdx.x;
  const int kc = bid & 7;
  const int dt = (bid >> 3) & 3;
  const int tt = (bid >> 5) & 7;
  const int b  = bid >> 8;
  const int wv = threadIdx.x >> 6;
  const int l  = threadIdx.x & 63;
  const int wm = wv >> 1, wn = wv & 1;
  const int t0 = tt * 64 + wm * 32;
  const int d0 = dt * 64 + wn * 32;
  const int m  = l & 15;
  const int q  = l >> 4;
  const int sc0 = kc * 128;

  f32x4 acc00 = {}, acc01 = {}, acc10 = {}, acc11 = {};
  const unsigned short* Arow = LinkTb + (size_t)(t0 + m) * 2048;
  const unsigned short* Brow = Bt + (size_t)(d0 + m) * 4096;

  #pragma unroll
  for (int seg = 0; seg < 2; ++seg) {
    const int acol = seg * 1024 + sc0 + q * 8;
    const int bcol = seg * 2048 + b * 1024 + sc0 + q * 8;
    #pragma unroll
    for (int ks = 0; ks < 4; ++ks) {
      const bf16x8 a0 = *(const bf16x8*)(Arow + acol + ks * 32);
      const bf16x8 a1 = *(const bf16x8*)(Arow + 16 * 2048 + acol + ks * 32);
      const bf16x8 b0 = *(const bf16x8*)(Brow + bcol + ks * 32);
      const bf16x8 b1 = *(const bf16x8*)(Brow + 16 * 4096 + bcol + ks * 32);
      acc00 = __builtin_amdgcn_mfma_f32_16x16x32_bf16(a0, b0, acc00, 0, 0, 0);
      acc01 = __builtin_amdgcn_mfma_f32_16x16x32_bf16(a0, b1, acc01, 0, 0, 0);
      acc10 = __builtin_amdgcn_mfma_f32_16x16x32_bf16(a1, b0, acc10, 0, 0, 0);
      acc11 = __builtin_amdgcn_mfma_f32_16x16x32_bf16(a1, b1, acc11, 0, 0, 0);
    }
  }

  float* pb = part + ((size_t)kc << 18) + (size_t)(b * 512 + t0 + q * 4) * D256 + d0 + m;
  #pragma unroll
  for (int reg = 0; reg < 4; ++reg) {
    pb[(0 + reg) * D256 + 0]       = acc00[reg];
    pb[(0 + reg) * D256 + 16]      = acc01[reg];
    pb[(16 + reg) * D256 + 0]      = acc10[reg];
    pb[(16 + reg) * D256 + 16]     = acc11[reg];
  }
}

// ---------------- k_Cred: sum the 8 K-chunk partials ----------------
__global__ __launch_bounds__(256) void k_Cred(const float* __restrict__ part,
                                              float* __restrict__ out) {
  const int row = blockIdx.x;   // 0..1023
  const int d   = threadIdx.x;
  float s = 0.f;
  #pragma unroll
  for (int kc = 0; kc < 8; ++kc)
    s += part[((size_t)kc << 18) + row * D256 + d];
  out[row * D256 + d] = s;
}

extern "C" void kernel_launch(void* const* d_in, const int* in_sizes, int n_in,
                              void* d_out, int out_size, void* d_ws, size_t ws_size,
                              hipStream_t stream) {
  const float* x       = (const float*)d_in[0];
  const float* M       = (const float*)d_in[1];
  const float* P       = (const float*)d_in[2];
  const float* Linker  = (const float*)d_in[3];
  const float* gamma   = (const float*)d_in[4];
  const float* beta    = (const float*)d_in[5];
  const float* resW    = (const float*)d_in[6];
  const float* rLinker = (const float*)d_in[7];
  float* out = (float*)d_out;

  char* ws = (char*)d_ws;
  float2*         MW     = (float2*)(ws);                          // 0.5 MB
  float4*         PIt4   = (float4*)(ws + 512 * 1024);             // 1 MB
  unsigned short* LinkTb = (unsigned short*)(ws + 1536 * 1024);    // 2 MB
  unsigned short* Bt     = (unsigned short*)(ws + 3584 * 1024);    // 2 MB
  float*          part   = (float*)(ws + 5632 * 1024);             // 8 MB

  hipLaunchKernelGGL(k_prep, dim3(512),  dim3(256),  0, stream,
                     M, resW, P, Linker, rLinker, MW, PIt4, LinkTb);
  hipLaunchKernelGGL(k_AB,   dim3(256),  dim3(1024), 0, stream,
                     x, MW, PIt4, gamma, beta, Bt);
  hipLaunchKernelGGL(k_Cm,   dim3(512),  dim3(256),  0, stream, LinkTb, Bt, part);
  hipLaunchKernelGGL(k_Cred, dim3(1024), dim3(256),  0, stream, part, out);
}